// Round 6
// baseline (262.928 us; speedup 1.0000x reference)
//
#include <hip/hip_runtime.h>
#include <hip/hip_bf16.h>

#define N_NODES  100000
#define N_EDGES  1600000
#define N_GRAPHS 128
#define HID      64
#define NBUCK    256
#define NPB      391                 // nodes per bucket: ceil(100000/256)
#define CAP      8192                // per-bucket record capacity (mean 6250)
#define BLKA     1024
#define EPTA     4
#define EPBA     (BLKA * EPTA)       // 4096 edges per pass-A block
#define NBLKA    ((N_EDGES + EPBA - 1) / EPBA)   // 391
#define BLK      1024
#define WPB      (BLK / 64)          // 16 waves per block
#define NBLK     512
#define NWAVES   (NBLK * WPB)        // 8192
#define CWORK    16                  // per-node fixed-cost weight for balancing
#define WSTRIDE  66                  // transposed-weight LDS row stride (floats)

// ---------------- Pass A: block-local LDS counting sort into 256 dst-range buckets ----------------
__global__ __launch_bounds__(1024) void bucketA(const int* __restrict__ src,
                                                const int* __restrict__ dst,
                                                int* __restrict__ bcnt,      // [NBUCK*16], line-padded
                                                int2* __restrict__ bbuf) {   // [NBUCK*CAP]
    __shared__ int cnt[NBUCK], scn[NBUCK], cur[NBUCK], gb[NBUCK];
    __shared__ int2 srt[EPBA];                    // 32 KB
    int tid = threadIdx.x;
    if (tid < NBUCK) cnt[tid] = 0;
    __syncthreads();

    int e0 = (blockIdx.x * BLKA + tid) * EPTA;
    int s[EPTA], d[EPTA], b[EPTA];
    int nv = 0;
    if (e0 + EPTA <= N_EDGES) {
        int4 s4 = *reinterpret_cast<const int4*>(src + e0);
        int4 d4 = *reinterpret_cast<const int4*>(dst + e0);
        s[0] = s4.x; s[1] = s4.y; s[2] = s4.z; s[3] = s4.w;
        d[0] = d4.x; d[1] = d4.y; d[2] = d4.z; d[3] = d4.w;
        nv = EPTA;
    } else {
        for (int e = e0; e < N_EDGES; ++e) { s[nv] = src[e]; d[nv] = dst[e]; ++nv; }
    }
    for (int k = 0; k < nv; ++k) {
        b[k] = (int)((unsigned)d[k] / (unsigned)NPB);
        atomicAdd(&cnt[b[k]], 1);
    }
    __syncthreads();

    if (tid < NBUCK) scn[tid] = cnt[tid];
    __syncthreads();
    for (int o = 1; o < NBUCK; o <<= 1) {
        int v = 0;
        if (tid < NBUCK && tid >= o) v = scn[tid - o];
        __syncthreads();
        if (tid < NBUCK && tid >= o) scn[tid] += v;
        __syncthreads();
    }
    if (tid < NBUCK) {
        int ex = scn[tid] - cnt[tid];
        cur[tid] = ex;
        gb[tid] = (cnt[tid] > 0) ? atomicAdd(&bcnt[tid * 16], cnt[tid]) : 0;
        scn[tid] = ex;
    }
    __syncthreads();

    for (int k = 0; k < nv; ++k) {
        int p = atomicAdd(&cur[b[k]], 1);
        srt[p] = make_int2(s[k], d[k]);
    }
    __syncthreads();

    int tot = scn[NBUCK - 1] + cnt[NBUCK - 1];
    for (int i = tid; i < tot; i += BLKA) {
        int2 r = srt[i];
        int bb = (int)((unsigned)r.y / (unsigned)NPB);
        bbuf[(size_t)bb * CAP + gb[bb] + (i - scn[bb])] = r;
    }
}

// ---------------- bucket base scan ----------------
__global__ __launch_bounds__(256) void scanBuck(const int* __restrict__ bcnt,
                                                int* __restrict__ bbase,
                                                int* __restrict__ off) {
    __shared__ int s[NBUCK];
    int t = threadIdx.x;
    int own = bcnt[t * 16];
    s[t] = own;
    __syncthreads();
    for (int o = 1; o < NBUCK; o <<= 1) {
        int v = (t >= o) ? s[t - o] : 0;
        __syncthreads();
        s[t] += v;
        __syncthreads();
    }
    bbase[t] = s[t] - own;
    if (t == NBUCK - 1) {
        bbase[NBUCK] = s[t];
        off[N_NODES] = s[t];
    }
}

// ---------------- Pass B: per-bucket CSR via LDS histogram + scan ----------------
__global__ __launch_bounds__(1024) void bucketB(const int2* __restrict__ bbuf,
                                                const int* __restrict__ bcnt,
                                                const int* __restrict__ bbase,
                                                int* __restrict__ off,
                                                int* __restrict__ esrc) {
    __shared__ int hist[NPB], scn[NPB], cur[NPB];
    int b = blockIdx.x, tid = threadIdx.x;
    int node0 = b * NPB;
    int ncnt = N_NODES - node0; if (ncnt > NPB) ncnt = NPB;
    if (tid < ncnt) hist[tid] = 0;
    __syncthreads();

    int cnt  = bcnt[b * 16];
    int base = bbase[b];
    const int2* buf = bbuf + (size_t)b * CAP;

    for (int i = tid; i < cnt; i += 1024)
        atomicAdd(&hist[buf[i].y - node0], 1);
    __syncthreads();

    if (tid < ncnt) scn[tid] = hist[tid];
    __syncthreads();
    for (int o = 1; o < NPB; o <<= 1) {
        int v = 0;
        if (tid < ncnt && tid >= o) v = scn[tid - o];
        __syncthreads();
        if (tid < ncnt && tid >= o) scn[tid] += v;
        __syncthreads();
    }
    if (tid < ncnt) {
        int ex = scn[tid] - hist[tid];
        off[node0 + tid] = base + ex;
        cur[tid] = ex;
    }
    __syncthreads();

    for (int i = tid; i < cnt; i += 1024) {
        int2 r = buf[i];
        int p = atomicAdd(&cur[r.y - node0], 1);
        esrc[base + p] = r.x;
    }
}

// ---------------- balanced node-range bound: smallest n with off[n]+CWORK*n >= target ----------------
__device__ __forceinline__ int part_bound(const int* __restrict__ off, long long target) {
    int lo = 0, hi = N_NODES;
    while (lo < hi) {
        int mid = (lo + hi) >> 1;
        long long v = (long long)off[mid] + (long long)CWORK * mid;
        if (v < target) lo = mid + 1; else hi = mid;
    }
    return lo;
}

// ---------------- Layer 1 fused: wave-per-node gather(x) + MLP1 -> h1 (bf16) ----------------
__global__ __launch_bounds__(1024, 8) void l1_fused(const float* __restrict__ x,
                                                    const int* __restrict__ off,
                                                    const int* __restrict__ esrc,
                                                    const float* __restrict__ W1a,
                                                    const float* __restrict__ b1a,
                                                    const float* __restrict__ W1b,
                                                    const float* __restrict__ b1b,
                                                    __hip_bfloat16* __restrict__ h1b) {
    __shared__ float sWa[3 * 64];
    __shared__ float sWbT[64 * WSTRIDE];          // transposed: sWbT[l][k] = W1b[k][l]
    __shared__ float sba[64], sbb[64];
    __shared__ float st_w[WPB][64];

    int tid = threadIdx.x;
    for (int i = tid; i < 3 * 64; i += BLK) sWa[i] = W1a[i];
    for (int i = tid; i < 64 * 64; i += BLK) {
        int k = i >> 6, l = i & 63;
        sWbT[l * WSTRIDE + k] = W1b[i];
    }
    if (tid < 64) { sba[tid] = b1a[tid]; sbb[tid] = b1b[tid]; }
    __syncthreads();

    int w = tid >> 6;
    int j = tid & 63;
    int wid = blockIdx.x * WPB + w;

    const long long TOT = (long long)N_EDGES + (long long)CWORK * N_NODES;
    int n0 = part_bound(off, TOT * wid / NWAVES);
    int n1 = part_bound(off, TOT * (wid + 1) / NWAVES);

    for (int n = n0; n < n1; ++n) {
        int start = off[n], end = off[n + 1];
        float a0 = 0.f, a1 = 0.f, a2 = 0.f;
        for (int e = start + j; e < end; e += 64) {
            int s = esrc[e];
            a0 += x[s * 3 + 0];
            a1 += x[s * 3 + 1];
            a2 += x[s * 3 + 2];
        }
#pragma unroll
        for (int d = 1; d < 64; d <<= 1) {
            a0 += __shfl_xor(a0, d);
            a1 += __shfl_xor(a1, d);
            a2 += __shfl_xor(a2, d);
        }
        float in0 = x[n * 3 + 0] + a0;
        float in1 = x[n * 3 + 1] + a1;
        float in2 = x[n * 3 + 2] + a2;
        float t = sba[j] + in0 * sWa[j] + in1 * sWa[64 + j] + in2 * sWa[128 + j];
        st_w[w][j] = fmaxf(t, 0.0f);
        __builtin_amdgcn_wave_barrier();
        float acc = sbb[j];
        const float* rowb = &sWbT[j * WSTRIDE];
#pragma unroll
        for (int k = 0; k < 64; k += 2) {
            float2 wv = *reinterpret_cast<const float2*>(&rowb[k]);
            acc += st_w[w][k] * wv.x;
            acc += st_w[w][k + 1] * wv.y;
        }
        h1b[n * 64 + j] = __float2bfloat16(fmaxf(acc, 0.0f));
        __builtin_amdgcn_wave_barrier();
    }
}

// ---------------- Layer 2 fused: pipelined packed-bf16 gather + MLP2 -> h2 ----------------
__device__ __forceinline__ float bl_lo(unsigned u) { return __uint_as_float(u << 16); }
__device__ __forceinline__ float bl_hi(unsigned u) { return __uint_as_float(u & 0xffff0000u); }

__global__ __launch_bounds__(1024, 8) void l2_fused(const unsigned* __restrict__ h1p,  // [N_NODES*32] packed 2xbf16
                                                    const int* __restrict__ off,
                                                    const int* __restrict__ esrc,
                                                    const float* __restrict__ W2a,
                                                    const float* __restrict__ b2a,
                                                    const float* __restrict__ W2b,
                                                    const float* __restrict__ b2b,
                                                    float* __restrict__ h2) {
    __shared__ float sWaT[64 * WSTRIDE];          // sWaT[l][k] = W2a[k][l]
    __shared__ float sWbT[64 * WSTRIDE];
    __shared__ float sba[64], sbb[64];
    __shared__ float sin_w[WPB][64];
    __shared__ float st_w[WPB][64];

    int tid = threadIdx.x;
    for (int i = tid; i < 64 * 64; i += BLK) {
        int k = i >> 6, l = i & 63;
        sWaT[l * WSTRIDE + k] = W2a[i];
        sWbT[l * WSTRIDE + k] = W2b[i];
    }
    if (tid < 64) { sba[tid] = b2a[tid]; sbb[tid] = b2b[tid]; }
    __syncthreads();

    int w = tid >> 6;
    int l = tid & 63;
    int g = l >> 4;          // edge-slot group 0..3
    int q = l & 15;          // 8B chunk of row
    int wid = blockIdx.x * WPB + w;

    const long long TOT = (long long)N_EDGES + (long long)CWORK * N_NODES;
    int n0 = part_bound(off, TOT * wid / NWAVES);
    int n1 = part_bound(off, TOT * (wid + 1) / NWAVES);

    for (int n = n0; n < n1; ++n) {
        int start = off[n], end = off[n + 1];

        // terms t in [start-1, end); t==start-1 is the self row n.
        int t = start - 1;
        int tA = t + g, tB = t + 4 + g;
        int sA = n, sB = n;
        if (tA >= start && tA < end) sA = esrc[tA];
        if (tB < end) sB = esrc[tB];
        uint2 vA = *reinterpret_cast<const uint2*>(h1p + sA * 32 + 2 * q);
        uint2 vB = *reinterpret_cast<const uint2*>(h1p + sB * 32 + 2 * q);
        unsigned mA = (tA < end) ? 0xffffffffu : 0u;
        unsigned mB = (tB < end) ? 0xffffffffu : 0u;

        float a0 = 0.f, a1 = 0.f, a2 = 0.f, a3 = 0.f;
        while (t + 8 < end) {
            int t2 = t + 8;
            int tA2 = t2 + g, tB2 = t2 + 4 + g;     // both >= start+7 >= start
            int sA2 = n, sB2 = n;
            if (tA2 < end) sA2 = esrc[tA2];
            if (tB2 < end) sB2 = esrc[tB2];
            uint2 vA2 = *reinterpret_cast<const uint2*>(h1p + sA2 * 32 + 2 * q);
            uint2 vB2 = *reinterpret_cast<const uint2*>(h1p + sB2 * 32 + 2 * q);
            unsigned mA2 = (tA2 < end) ? 0xffffffffu : 0u;
            unsigned mB2 = (tB2 < end) ? 0xffffffffu : 0u;

            a0 += bl_lo(vA.x & mA) + bl_lo(vB.x & mB);
            a1 += bl_hi(vA.x & mA) + bl_hi(vB.x & mB);
            a2 += bl_lo(vA.y & mA) + bl_lo(vB.y & mB);
            a3 += bl_hi(vA.y & mA) + bl_hi(vB.y & mB);

            vA = vA2; vB = vB2; mA = mA2; mB = mB2; t = t2;
        }
        a0 += bl_lo(vA.x & mA) + bl_lo(vB.x & mB);
        a1 += bl_hi(vA.x & mA) + bl_hi(vB.x & mB);
        a2 += bl_lo(vA.y & mA) + bl_lo(vB.y & mB);
        a3 += bl_hi(vA.y & mA) + bl_hi(vB.y & mB);

        // fold the 4 edge-slot groups (lane bits 4,5)
        a0 += __shfl_xor(a0, 16); a0 += __shfl_xor(a0, 32);
        a1 += __shfl_xor(a1, 16); a1 += __shfl_xor(a1, 32);
        a2 += __shfl_xor(a2, 16); a2 += __shfl_xor(a2, 32);
        a3 += __shfl_xor(a3, 16); a3 += __shfl_xor(a3, 32);

        // lane writes feature 4*q + g (bijective over 0..63)
        float outv = (g == 0) ? a0 : (g == 1) ? a1 : (g == 2) ? a2 : a3;
        sin_w[w][4 * q + g] = outv;
        __builtin_amdgcn_wave_barrier();

        float tacc = sba[l];
        const float* rowa = &sWaT[l * WSTRIDE];
#pragma unroll
        for (int k = 0; k < 64; k += 2) {
            float2 wv = *reinterpret_cast<const float2*>(&rowa[k]);
            tacc += sin_w[w][k] * wv.x;
            tacc += sin_w[w][k + 1] * wv.y;
        }
        st_w[w][l] = fmaxf(tacc, 0.0f);
        __builtin_amdgcn_wave_barrier();

        float o = sbb[l];
        const float* rowb = &sWbT[l * WSTRIDE];
#pragma unroll
        for (int k = 0; k < 64; k += 2) {
            float2 wv = *reinterpret_cast<const float2*>(&rowb[k]);
            o += st_w[w][k] * wv.x;
            o += st_w[w][k + 1] * wv.y;
        }
        h2[n * 64 + l] = fmaxf(o, 0.0f);
        __builtin_amdgcn_wave_barrier();
    }
}

// ---------------- Global mean pool ----------------
__global__ __launch_bounds__(256) void pool(const float* __restrict__ h2,
                                            const int* __restrict__ batch,
                                            float* __restrict__ out) {
    int g = blockIdx.x;
    int lo = 0, hi = N_NODES;
    while (lo < hi) { int mid = (lo + hi) >> 1; if (batch[mid] < g) lo = mid + 1; else hi = mid; }
    int start = lo;
    lo = start; hi = N_NODES;
    while (lo < hi) { int mid = (lo + hi) >> 1; if (batch[mid] < g + 1) lo = mid + 1; else hi = mid; }
    int end = lo;

    int j = threadIdx.x & 63;
    int r = threadIdx.x >> 6;
    float local = 0.0f;
    for (int n = start + r; n < end; n += 4)
        local += h2[n * 64 + j];

    __shared__ float red[4][64];
    red[r][j] = local;
    __syncthreads();
    if (r == 0) {
        float s = red[0][j] + red[1][j] + red[2][j] + red[3][j];
        float cnt = (float)((end - start) > 1 ? (end - start) : 1);
        out[g * 64 + j] = s / cnt;
    }
}

extern "C" void kernel_launch(void* const* d_in, const int* in_sizes, int n_in,
                              void* d_out, int out_size, void* d_ws, size_t ws_size,
                              hipStream_t stream) {
    const float* x    = (const float*)d_in[0];
    const int*   ei   = (const int*)d_in[1];
    const int*   bat  = (const int*)d_in[2];
    const float* W1a  = (const float*)d_in[3];
    const float* b1a  = (const float*)d_in[4];
    const float* W1b  = (const float*)d_in[5];
    const float* b1b  = (const float*)d_in[6];
    const float* W2a  = (const float*)d_in[7];
    const float* b2a  = (const float*)d_in[8];
    const float* W2b  = (const float*)d_in[9];
    const float* b2b  = (const float*)d_in[10];
    float* out = (float*)d_out;

    const int* src = ei;
    const int* dst = ei + N_EDGES;

    char* ws = (char*)d_ws;
    auto alignup = [](size_t v) { return (v + 255) & ~(size_t)255; };
    int*   bcnt  = (int*)ws;                       ws += alignup((size_t)NBUCK * 16 * 4);
    int*   bbase = (int*)ws;                       ws += alignup((size_t)(NBUCK + 1) * 4);
    int*   off   = (int*)ws;                       ws += alignup((size_t)(N_NODES + 1) * 4);
    int*   esrc  = (int*)ws;                       ws += alignup((size_t)N_EDGES * 4);
    __hip_bfloat16* h1b = (__hip_bfloat16*)ws;     ws += alignup((size_t)N_NODES * HID * 2);
    // bbuf and h2 share a slab: bbuf dead before l2_fused writes h2
    int2*  bbuf  = (int2*)ws;
    float* h2    = (float*)ws;

    hipMemsetAsync(bcnt, 0, (size_t)NBUCK * 16 * 4, stream);

    bucketA<<<NBLKA, BLKA, 0, stream>>>(src, dst, bcnt, bbuf);
    scanBuck<<<1, 256, 0, stream>>>(bcnt, bbase, off);
    bucketB<<<NBUCK, 1024, 0, stream>>>(bbuf, bcnt, bbase, off, esrc);

    l1_fused<<<NBLK, BLK, 0, stream>>>(x, off, esrc, W1a, b1a, W1b, b1b, h1b);
    l2_fused<<<NBLK, BLK, 0, stream>>>((const unsigned*)h1b, off, esrc, W2a, b2a, W2b, b2b, h2);
    pool<<<N_GRAPHS, 256, 0, stream>>>(h2, bat, out);
}